// Round 3
// 731.635 us; speedup vs baseline: 1.1229x; 1.1229x over previous
//
#include <hip/hip_runtime.h>
#include <hip/hip_bf16.h>

#define NNODES 50000
#define NEDGES 800000
#define ETOT   (NNODES + NEDGES)

typedef __attribute__((ext_vector_type(8))) short short8;
typedef __attribute__((ext_vector_type(4))) float floatx4;
typedef __attribute__((ext_vector_type(2))) unsigned int uint2v;

__device__ __forceinline__ float bf2f(__hip_bfloat16 x) { return __bfloat162float(x); }
__device__ __forceinline__ __hip_bfloat16 f2bf(float f) { return __float2bfloat16(f); }
__device__ __forceinline__ float sane(float v, float c) {
  v = (v == v) ? v : 0.f;
  return fminf(fmaxf(v, -c), c);
}

// ---------------- utility ----------------
__global__ void zero_int_kernel(int* __restrict__ p, int n) {
  int i = blockIdx.x * blockDim.x + threadIdx.x;
  if (i < n) p[i] = 0;
}
__global__ void fill_out_kernel(float* __restrict__ o, int n, float v) {
  int i = blockIdx.x * blockDim.x + threadIdx.x;
  if (i < n) o[i] = v;
}
__global__ void split_input_kernel(const float* __restrict__ in,
                                   __hip_bfloat16* __restrict__ hi,
                                   __hip_bfloat16* __restrict__ lo, int n) {
  int i = blockIdx.x * blockDim.x + threadIdx.x;
  if (i >= n) return;
  float v = sane(in[i], 1e4f);
  __hip_bfloat16 h = f2bf(v);
  hi[i] = h;
  lo[i] = f2bf(v - bf2f(h));
}
// pad 47-vec attention params to 64 with zeros
__global__ void pad47_kernel(const float* __restrict__ a, const float* __restrict__ b,
                             float* __restrict__ ap, float* __restrict__ bp) {
  int i = threadIdx.x;  // 64
  ap[i] = (i < 47) ? sane(a[i], 1e4f) : 0.f;
  bp[i] = (i < 47) ? sane(b[i], 1e4f) : 0.f;
}

// ---------------- CSR build (dst-sorted) ----------------
__global__ void degree_kernel(const int* __restrict__ ei, int* __restrict__ deg) {
  int p = blockIdx.x * blockDim.x + threadIdx.x;
  if (p >= ETOT) return;
  int dst = (p < NEDGES) ? ei[NEDGES + p] : (p - NEDGES);
  dst = min(max(dst, 0), NNODES - 1);
  atomicAdd(&deg[dst], 1);
}

__global__ __launch_bounds__(1024) void scan_kernel(const int* __restrict__ deg,
                                                    int* __restrict__ row_ptr,
                                                    int* __restrict__ cursor) {
  __shared__ int sh[1024];
  int t = threadIdx.x;
  const int n = NNODES;
  const int chunk = (n + 1023) / 1024;  // 49
  int beg = min(n, t * chunk);
  int end = min(n, beg + chunk);
  int s = 0;
  for (int i = beg; i < end; ++i) s += deg[i];
  sh[t] = s;
  __syncthreads();
  for (int off = 1; off < 1024; off <<= 1) {
    int v = (t >= off) ? sh[t - off] : 0;
    __syncthreads();
    sh[t] += v;
    __syncthreads();
  }
  int run = sh[t] - s;  // exclusive prefix
  for (int i = beg; i < end; ++i) {
    int d = deg[i];
    row_ptr[i] = run;
    cursor[i] = run;
    run += d;
  }
  if (t == 1023) row_ptr[n] = sh[1023];
}

__global__ void scatter_kernel(const int* __restrict__ ei, int* __restrict__ cursor,
                               int* __restrict__ csr_src) {
  int p = blockIdx.x * blockDim.x + threadIdx.x;
  if (p >= ETOT) return;
  int src, dst;
  if (p < NEDGES) { src = ei[p]; dst = ei[NEDGES + p]; }
  else            { src = p - NEDGES; dst = src; }
  src = min(max(src, 0), NNODES - 1);
  dst = min(max(dst, 0), NNODES - 1);
  int pos = atomicAdd(&cursor[dst], 1);
  pos = min(max(pos, 0), ETOT - 1);
  csr_src[pos] = src;
}

// ---------------- weight pack (W [K][Nreal] f32 -> fragment-packed W^T) -------
// Packed layout: elem(n, k) -> idx = ((nt*KCH + kk32)*64 + quad*16 + m)*8 + j
//   nt = n>>4, m = n&15, kk32 = k>>5, quad = (k>>3)&3, j = k&7
// so a wave's MFMA B fragment (lane = quad*16+m) is one contiguous 1KB chunk.
__global__ void pack_w_kernel(const float* __restrict__ W,
                              __hip_bfloat16* __restrict__ Bh,
                              __hip_bfloat16* __restrict__ Bl,
                              int K, int Nreal, int Npad) {
  int idx = blockIdx.x * blockDim.x + threadIdx.x;
  if (idx >= Npad * K) return;
  int e = idx;
  int j = e & 7;    e >>= 3;
  int m = e & 15;   e >>= 4;
  int quad = e & 3; e >>= 2;
  int kch = K >> 5;
  int kk32 = e % kch;
  int nt = e / kch;
  int n = nt * 16 + m;
  int k = kk32 * 32 + quad * 8 + j;
  float v = (n < Nreal) ? sane(W[k * Nreal + n], 1e4f) : 0.f;
  __hip_bfloat16 h = f2bf(v);
  Bh[idx] = h;
  Bl[idx] = f2bf(v - bf2f(h));
}

// ---------------- GEMM + fused attention logits ----------------
// Identical to the round-0 (passing) kernel except B is fragment-packed:
// each B load is one contiguous 1KB wave transaction instead of a 16-row
// strided gather. Values and MFMA ordering are bitwise identical to round 0.
// A-frag: m=lane&15, k=quad*8+j. C/D: col=lane&15, row=quad*4+r.
template<int KDIM, int NOUT, int HEADS>
__global__ __launch_bounds__(256) void gemm_attn_kernel(
    const __hip_bfloat16* __restrict__ Ah, const __hip_bfloat16* __restrict__ Al,
    const __hip_bfloat16* __restrict__ Bh, const __hip_bfloat16* __restrict__ Bl,
    const float* __restrict__ asv, const float* __restrict__ adv,
    __hip_bfloat16* __restrict__ Ch, float* __restrict__ als, float* __restrict__ ald,
    int M) {
  constexpr int NT = NOUT / 16;
  constexpr int KCH = KDIM / 32;
  constexpr int TPH = NT / HEADS;  // MFMA col-tiles per head
  int wave = threadIdx.x >> 6;
  int lane = threadIdx.x & 63;
  int row0 = blockIdx.x * 64 + wave * 16;
  if (row0 >= M) return;
  int m = lane & 15, quad = lane >> 4;
  size_t aoff = (size_t)(row0 + m) * KDIM + quad * 8;

  const short8* Bph = reinterpret_cast<const short8*>(Bh);
  const short8* Bpl = reinterpret_cast<const short8*>(Bl);

  floatx4 acc[NT];
#pragma unroll
  for (int nt = 0; nt < NT; ++nt) acc[nt] = (floatx4){0.f, 0.f, 0.f, 0.f};

#pragma unroll
  for (int kk = 0; kk < KCH; ++kk) {
    short8 ah = *reinterpret_cast<const short8*>(Ah + aoff + kk * 32);
    short8 al = *reinterpret_cast<const short8*>(Al + aoff + kk * 32);
#pragma unroll
    for (int nt = 0; nt < NT; ++nt) {
      size_t o = ((size_t)nt * KCH + kk) * 64 + lane;
      short8 bh = Bph[o];
      short8 bl = Bpl[o];
      acc[nt] = __builtin_amdgcn_mfma_f32_16x16x32_bf16(ah, bh, acc[nt], 0, 0, 0);
      acc[nt] = __builtin_amdgcn_mfma_f32_16x16x32_bf16(ah, bl, acc[nt], 0, 0, 0);
      acc[nt] = __builtin_amdgcn_mfma_f32_16x16x32_bf16(al, bh, acc[nt], 0, 0, 0);
    }
  }

  // fused attention logits
  float asl[NT], adl[NT];
#pragma unroll
  for (int nt = 0; nt < NT; ++nt) {
    asl[nt] = asv[nt * 16 + m];
    adl[nt] = adv[nt * 16 + m];
  }
  float ps[4 * HEADS], pd[4 * HEADS];
#pragma unroll
  for (int i = 0; i < 4 * HEADS; ++i) { ps[i] = 0.f; pd[i] = 0.f; }
#pragma unroll
  for (int nt = 0; nt < NT; ++nt) {
    int h = nt / TPH;
#pragma unroll
    for (int r = 0; r < 4; ++r) {
      ps[r * HEADS + h] += acc[nt][r] * asl[nt];
      pd[r * HEADS + h] += acc[nt][r] * adl[nt];
    }
  }
#pragma unroll
  for (int off = 1; off < 16; off <<= 1) {
#pragma unroll
    for (int i = 0; i < 4 * HEADS; ++i) {
      ps[i] += __shfl_xor(ps[i], off);
      pd[i] += __shfl_xor(pd[i], off);
    }
  }
  if (m == 0) {
#pragma unroll
    for (int r = 0; r < 4; ++r)
#pragma unroll
      for (int h = 0; h < HEADS; ++h) {
        int row = row0 + quad * 4 + r;
        als[(size_t)row * HEADS + h] = sane(ps[r * HEADS + h], 80.f);
        ald[(size_t)row * HEADS + h] = sane(pd[r * HEADS + h], 80.f);
      }
  }

  // store C (hi-only bf16)
#pragma unroll
  for (int nt = 0; nt < NT; ++nt)
#pragma unroll
    for (int r = 0; r < 4; ++r) {
      float v = sane(acc[nt][r], 3e4f);
      Ch[(size_t)(row0 + quad * 4 + r) * NOUT + nt * 16 + m] = f2bf(v);
    }
}

// ---------------- normalized edge weights (alpha) ----------------
// one wave per dst node; lane-per-edge; shuffle-reduce denominators
template<int H>
__global__ __launch_bounds__(256) void alpha_kernel(const int* __restrict__ row_ptr,
                                                    const int* __restrict__ csr_src,
                                                    const float* __restrict__ als,
                                                    const float* __restrict__ ald,
                                                    float* __restrict__ alpha) {
  int wid = threadIdx.x >> 6, lane = threadIdx.x & 63;
  int dst = blockIdx.x * 4 + wid;
  if (dst >= NNODES) return;
  int start = row_ptr[dst], end = row_ptr[dst + 1];
  int cnt = end - start;
  if (cnt <= 0) return;
  float adv[H];
#pragma unroll
  for (int h = 0; h < H; ++h) adv[h] = ald[(size_t)dst * H + h];

  if (cnt <= 64) {
    int i = start + lane;
    bool valid = lane < cnt;
    int s = valid ? min(max(csr_src[i], 0), NNODES - 1) : 0;
    float w[H];
#pragma unroll
    for (int h = 0; h < H; ++h) {
      float e = als[(size_t)s * H + h] + adv[h];
      e = e > 0.f ? e : 0.2f * e;
      e = fminf(fmaxf(e, -80.f), 80.f);
      w[h] = valid ? __expf(e) : 0.f;
    }
#pragma unroll
    for (int h = 0; h < H; ++h) {
      float v = w[h];
#pragma unroll
      for (int off = 1; off < 64; off <<= 1) v += __shfl_xor(v, off);
      float inv = 1.f / fmaxf(v, 1e-30f);
      if (valid) alpha[(size_t)i * H + h] = w[h] * inv;
    }
  } else {
    float dl[H];
#pragma unroll
    for (int h = 0; h < H; ++h) dl[h] = 0.f;
    for (int base = start; base < end; base += 64) {
      int i = base + lane;
      bool valid = i < end;
      int s = valid ? min(max(csr_src[i], 0), NNODES - 1) : 0;
#pragma unroll
      for (int h = 0; h < H; ++h) {
        float e = als[(size_t)s * H + h] + adv[h];
        e = e > 0.f ? e : 0.2f * e;
        e = fminf(fmaxf(e, -80.f), 80.f);
        float w = valid ? __expf(e) : 0.f;
        dl[h] += w;
        if (valid) alpha[(size_t)i * H + h] = w;
      }
    }
    float inv[H];
#pragma unroll
    for (int h = 0; h < H; ++h) {
      float v = dl[h];
#pragma unroll
      for (int off = 1; off < 64; off <<= 1) v += __shfl_xor(v, off);
      inv[h] = 1.f / fmaxf(v, 1e-30f);
    }
    for (int base = start; base < end; base += 64) {
      int i = base + lane;
      if (i < end)
#pragma unroll
        for (int h = 0; h < H; ++h) alpha[(size_t)i * H + h] *= inv[h];
    }
  }
}

// ---------------- aggregation, mid layers (T=256, H=4) ----------------
// block = 4 waves per dst; lane owns 4 cols (one dwordx2 bf16x4 load);
// waves stride edges; LDS cross-wave reduce; ELU + hi/lo split epilogue.
__global__ __launch_bounds__(256) void agg_mid_kernel(const int* __restrict__ row_ptr,
                                                      const int* __restrict__ csr_src,
                                                      const __hip_bfloat16* __restrict__ Fh,
                                                      const float* __restrict__ alpha,
                                                      const float* __restrict__ bias,
                                                      __hip_bfloat16* __restrict__ Oh,
                                                      __hip_bfloat16* __restrict__ Ol) {
  __shared__ float part[4][256];
  int dst = blockIdx.x;
  int wid = threadIdx.x >> 6, lane = threadIdx.x & 63;
  int start = row_ptr[dst], end = row_ptr[dst + 1];
  int cnt = end - start;
  int head = lane >> 4;
  float a0 = 0.f, a1 = 0.f, a2 = 0.f, a3 = 0.f;
  int p = wid;
  for (; p + 4 < cnt; p += 8) {  // 2 edges in flight per wave
    int e0 = start + p, e1 = start + p + 4;
    int s0 = csr_src[e0], s1 = csr_src[e1];
    float w0 = alpha[(size_t)e0 * 4 + head];
    float w1 = alpha[(size_t)e1 * 4 + head];
    uint2v f0 = *reinterpret_cast<const uint2v*>(Fh + (size_t)s0 * 256 + lane * 4);
    uint2v f1 = *reinterpret_cast<const uint2v*>(Fh + (size_t)s1 * 256 + lane * 4);
    a0 += w0 * __uint_as_float(f0.x << 16);
    a1 += w0 * __uint_as_float(f0.x & 0xffff0000u);
    a2 += w0 * __uint_as_float(f0.y << 16);
    a3 += w0 * __uint_as_float(f0.y & 0xffff0000u);
    a0 += w1 * __uint_as_float(f1.x << 16);
    a1 += w1 * __uint_as_float(f1.x & 0xffff0000u);
    a2 += w1 * __uint_as_float(f1.y << 16);
    a3 += w1 * __uint_as_float(f1.y & 0xffff0000u);
  }
  for (; p < cnt; p += 4) {
    int e0 = start + p;
    int s0 = csr_src[e0];
    float w0 = alpha[(size_t)e0 * 4 + head];
    uint2v f0 = *reinterpret_cast<const uint2v*>(Fh + (size_t)s0 * 256 + lane * 4);
    a0 += w0 * __uint_as_float(f0.x << 16);
    a1 += w0 * __uint_as_float(f0.x & 0xffff0000u);
    a2 += w0 * __uint_as_float(f0.y << 16);
    a3 += w0 * __uint_as_float(f0.y & 0xffff0000u);
  }
  *reinterpret_cast<floatx4*>(&part[wid][lane * 4]) = (floatx4){a0, a1, a2, a3};
  __syncthreads();
  int t = threadIdx.x;
  float o = part[0][t] + part[1][t] + part[2][t] + part[3][t] + bias[t];
  o = o > 0.f ? o : __expf(o) - 1.f;  // ELU
  __hip_bfloat16 h = f2bf(o);
  Oh[(size_t)dst * 256 + t] = h;
  Ol[(size_t)dst * 256 + t] = f2bf(o - bf2f(h));
}

// ---------------- aggregation, final layer (64-pad feat, 47 out, fp32) ------
__global__ void agg_final_kernel(const int* __restrict__ row_ptr,
                                 const int* __restrict__ csr_src,
                                 const __hip_bfloat16* __restrict__ Fh,
                                 const float* __restrict__ alpha,
                                 const float* __restrict__ bias,
                                 float* __restrict__ out) {
  int wid = threadIdx.x >> 6, lane = threadIdx.x & 63;
  int dst = blockIdx.x * 4 + wid;
  if (dst >= NNODES) return;
  int start = row_ptr[dst], end = row_ptr[dst + 1];
  float acc = 0.f;
  int e = start;
  for (; e + 1 < end; e += 2) {
    int s0 = csr_src[e], s1 = csr_src[e + 1];
    float w0 = alpha[e], w1 = alpha[e + 1];
    float f0 = bf2f(Fh[(size_t)s0 * 64 + lane]);
    float f1 = bf2f(Fh[(size_t)s1 * 64 + lane]);
    acc += w0 * f0 + w1 * f1;
  }
  for (; e < end; ++e) {
    int s0 = csr_src[e];
    acc += alpha[e] * bf2f(Fh[(size_t)s0 * 64 + lane]);
  }
  if (lane < 47) out[(size_t)dst * 47 + lane] = acc + bias[lane];
}

// ---------------- launch ----------------
extern "C" void kernel_launch(void* const* d_in, const int* in_sizes, int n_in,
                              void* d_out, int out_size, void* d_ws, size_t ws_size,
                              hipStream_t stream) {
  const float* x   = (const float*)d_in[0];
  const int* ei    = (const int*)d_in[1];
  const float* W1  = (const float*)d_in[2];
  const float* a1s = (const float*)d_in[3];
  const float* a1d = (const float*)d_in[4];
  const float* b1  = (const float*)d_in[5];
  const float* W2  = (const float*)d_in[6];
  const float* a2s = (const float*)d_in[7];
  const float* a2d = (const float*)d_in[8];
  const float* b2  = (const float*)d_in[9];
  const float* W3  = (const float*)d_in[10];
  const float* a3s = (const float*)d_in[11];
  const float* a3d = (const float*)d_in[12];
  const float* b3  = (const float*)d_in[13];
  float* out = (float*)d_out;
  (void)n_in; (void)in_sizes;

  char* base = (char*)d_ws;
  size_t off = 0;
  auto alloc = [&](size_t bytes) -> char* {
    off = (off + 255) & ~(size_t)255;
    char* p = base + off;
    off += bytes;
    return p;
  };
  int* deg     = (int*)alloc((size_t)NNODES * 4);
  int* cursor  = (int*)alloc((size_t)NNODES * 4);
  int* row_ptr = (int*)alloc((size_t)(NNODES + 1) * 4);
  int* csr_src = (int*)alloc((size_t)ETOT * 4);
  float* als   = (float*)alloc((size_t)NNODES * 4 * 4);
  float* ald   = (float*)alloc((size_t)NNODES * 4 * 4);
  float* alpha = (float*)alloc((size_t)ETOT * 4 * 4);
  __hip_bfloat16* Ah = (__hip_bfloat16*)alloc((size_t)NNODES * 256 * 2);
  __hip_bfloat16* Al = (__hip_bfloat16*)alloc((size_t)NNODES * 256 * 2);
  __hip_bfloat16* Fh = (__hip_bfloat16*)alloc((size_t)NNODES * 256 * 2);
  __hip_bfloat16* wth = (__hip_bfloat16*)alloc((size_t)256 * 256 * 2);
  __hip_bfloat16* wtl = (__hip_bfloat16*)alloc((size_t)256 * 256 * 2);
  float* asv3 = (float*)alloc(64 * 4);
  float* adv3 = (float*)alloc(64 * 4);

  if (ws_size < off) {
    fill_out_kernel<<<(out_size + 255) / 256, 256, 0, stream>>>(out, out_size, 12345.f);
    return;
  }

  // CSR build (shared by all layers)
  zero_int_kernel<<<(NNODES + 255) / 256, 256, 0, stream>>>(deg, NNODES);
  degree_kernel<<<(ETOT + 255) / 256, 256, 0, stream>>>(ei, deg);
  scan_kernel<<<1, 1024, 0, stream>>>(deg, row_ptr, cursor);
  scatter_kernel<<<(ETOT + 255) / 256, 256, 0, stream>>>(ei, cursor, csr_src);

  const int gemm_grid = (NNODES + 63) / 64;
  split_input_kernel<<<(NNODES * 128 + 255) / 256, 256, 0, stream>>>(x, Ah, Al, NNODES * 128);
  pad47_kernel<<<1, 64, 0, stream>>>(a3s, a3d, asv3, adv3);

  // layer 1: 128 -> 4x64, ELU
  pack_w_kernel<<<(256 * 128 + 255) / 256, 256, 0, stream>>>(W1, wth, wtl, 128, 256, 256);
  gemm_attn_kernel<128, 256, 4><<<gemm_grid, 256, 0, stream>>>(Ah, Al, wth, wtl, a1s, a1d,
                                                               Fh, als, ald, NNODES);
  alpha_kernel<4><<<(NNODES + 3) / 4, 256, 0, stream>>>(row_ptr, csr_src, als, ald, alpha);
  agg_mid_kernel<<<NNODES, 256, 0, stream>>>(row_ptr, csr_src, Fh, alpha, b1, Ah, Al);

  // layer 2: 256 -> 4x64, ELU
  pack_w_kernel<<<(256 * 256 + 255) / 256, 256, 0, stream>>>(W2, wth, wtl, 256, 256, 256);
  gemm_attn_kernel<256, 256, 4><<<gemm_grid, 256, 0, stream>>>(Ah, Al, wth, wtl, a2s, a2d,
                                                               Fh, als, ald, NNODES);
  alpha_kernel<4><<<(NNODES + 3) / 4, 256, 0, stream>>>(row_ptr, csr_src, als, ald, alpha);
  agg_mid_kernel<<<NNODES, 256, 0, stream>>>(row_ptr, csr_src, Fh, alpha, b2, Ah, Al);

  // layer 3: 256 -> 47 (pad 64), no ELU, fp32 out
  pack_w_kernel<<<(64 * 256 + 255) / 256, 256, 0, stream>>>(W3, wth, wtl, 256, 47, 64);
  gemm_attn_kernel<256, 64, 1><<<gemm_grid, 256, 0, stream>>>(Ah, Al, wth, wtl, asv3, adv3,
                                                              Fh, als, ald, NNODES);
  alpha_kernel<1><<<(NNODES + 3) / 4, 256, 0, stream>>>(row_ptr, csr_src, als, ald, alpha);
  agg_final_kernel<<<(NNODES + 3) / 4, 256, 0, stream>>>(row_ptr, csr_src, Fh, alpha, b3, out);
}

// Round 4
// 726.952 us; speedup vs baseline: 1.1302x; 1.0064x over previous
//
#include <hip/hip_runtime.h>
#include <hip/hip_bf16.h>

#define NNODES 50000
#define NEDGES 800000
#define ETOT   (NNODES + NEDGES)
#define MTILES 3136            // row-tiles of 16: covers 50176 rows
#define MPAD   (MTILES * 16)   // 50176

typedef __attribute__((ext_vector_type(8))) short short8;
typedef __attribute__((ext_vector_type(4))) float floatx4;
typedef __attribute__((ext_vector_type(2))) unsigned int uint2v;

__device__ __forceinline__ float bf2f(__hip_bfloat16 x) { return __bfloat162float(x); }
__device__ __forceinline__ __hip_bfloat16 f2bf(float f) { return __float2bfloat16(f); }
__device__ __forceinline__ float sane(float v, float c) {
  v = (v == v) ? v : 0.f;
  return fminf(fmaxf(v, -c), c);
}

// ---------------- utility ----------------
__global__ void zero_int_kernel(int* __restrict__ p, int n) {
  int i = blockIdx.x * blockDim.x + threadIdx.x;
  if (i < n) p[i] = 0;
}
__global__ void fill_out_kernel(float* __restrict__ o, int n, float v) {
  int i = blockIdx.x * blockDim.x + threadIdx.x;
  if (i < n) o[i] = v;
}
__global__ void split_input_kernel(const float* __restrict__ in,
                                   __hip_bfloat16* __restrict__ hi,
                                   __hip_bfloat16* __restrict__ lo, int n) {
  int i = blockIdx.x * blockDim.x + threadIdx.x;
  if (i >= n) return;
  float v = sane(in[i], 1e4f);
  __hip_bfloat16 h = f2bf(v);
  hi[i] = h;
  lo[i] = f2bf(v - bf2f(h));
}
// zero the A-buffer tail so pad-row reads (any stride 128/256) see zeros:
// elements [NNODES*128, MPAD*256) of both hi and lo.
__global__ void zero_tail_kernel(__hip_bfloat16* __restrict__ hi,
                                 __hip_bfloat16* __restrict__ lo) {
  const int base = NNODES * 128;
  const int cnt = MPAD * 256 - base;
  int i = blockIdx.x * blockDim.x + threadIdx.x;
  if (i >= cnt) return;
  hi[base + i] = f2bf(0.f);
  lo[base + i] = f2bf(0.f);
}
// pad 47-vec attention params to 64 with zeros
__global__ void pad47_kernel(const float* __restrict__ a, const float* __restrict__ b,
                             float* __restrict__ ap, float* __restrict__ bp) {
  int i = threadIdx.x;  // 64
  ap[i] = (i < 47) ? sane(a[i], 1e4f) : 0.f;
  bp[i] = (i < 47) ? sane(b[i], 1e4f) : 0.f;
}

// ---------------- CSR build (dst-sorted) ----------------
__global__ void degree_kernel(const int* __restrict__ ei, int* __restrict__ deg) {
  int p = blockIdx.x * blockDim.x + threadIdx.x;
  if (p >= ETOT) return;
  int dst = (p < NEDGES) ? ei[NEDGES + p] : (p - NEDGES);
  dst = min(max(dst, 0), NNODES - 1);
  atomicAdd(&deg[dst], 1);
}

__global__ __launch_bounds__(1024) void scan_kernel(const int* __restrict__ deg,
                                                    int* __restrict__ row_ptr,
                                                    int* __restrict__ cursor) {
  __shared__ int sh[1024];
  int t = threadIdx.x;
  const int n = NNODES;
  const int chunk = (n + 1023) / 1024;  // 49
  int beg = min(n, t * chunk);
  int end = min(n, beg + chunk);
  int s = 0;
  for (int i = beg; i < end; ++i) s += deg[i];
  sh[t] = s;
  __syncthreads();
  for (int off = 1; off < 1024; off <<= 1) {
    int v = (t >= off) ? sh[t - off] : 0;
    __syncthreads();
    sh[t] += v;
    __syncthreads();
  }
  int run = sh[t] - s;  // exclusive prefix
  for (int i = beg; i < end; ++i) {
    int d = deg[i];
    row_ptr[i] = run;
    cursor[i] = run;
    run += d;
  }
  if (t == 1023) row_ptr[n] = sh[1023];
}

__global__ void scatter_kernel(const int* __restrict__ ei, int* __restrict__ cursor,
                               int* __restrict__ csr_src) {
  int p = blockIdx.x * blockDim.x + threadIdx.x;
  if (p >= ETOT) return;
  int src, dst;
  if (p < NEDGES) { src = ei[p]; dst = ei[NEDGES + p]; }
  else            { src = p - NEDGES; dst = src; }
  src = min(max(src, 0), NNODES - 1);
  dst = min(max(dst, 0), NNODES - 1);
  int pos = atomicAdd(&cursor[dst], 1);
  pos = min(max(pos, 0), ETOT - 1);
  csr_src[pos] = src;
}

// ---------------- weight pack (W [K][Nreal] f32 -> fragment-packed W^T) -------
// Packed layout: elem(n, k) -> idx = ((nt*KCH + kk32)*64 + quad*16 + m)*8 + j
//   nt = n>>4, m = n&15, kk32 = k>>5, quad = (k>>3)&3, j = k&7
// so a wave's MFMA B fragment (lane = quad*16+m) is one contiguous 1KB chunk.
__global__ void pack_w_kernel(const float* __restrict__ W,
                              __hip_bfloat16* __restrict__ Bh,
                              __hip_bfloat16* __restrict__ Bl,
                              int K, int Nreal, int Npad) {
  int idx = blockIdx.x * blockDim.x + threadIdx.x;
  if (idx >= Npad * K) return;
  int e = idx;
  int j = e & 7;    e >>= 3;
  int m = e & 15;   e >>= 4;
  int quad = e & 3; e >>= 2;
  int kch = K >> 5;
  int kk32 = e % kch;
  int nt = e / kch;
  int n = nt * 16 + m;
  int k = kk32 * 32 + quad * 8 + j;
  float v = (n < Nreal) ? sane(W[k * Nreal + n], 1e4f) : 0.f;
  __hip_bfloat16 h = f2bf(v);
  Bh[idx] = h;
  Bl[idx] = f2bf(v - bf2f(h));
}

// ---------------- GEMM + fused attention logits ----------------
// A row-major (verified r0 path), B fragment-packed (verified r3 path).
// Register blocking: each wave owns RT=4 row-tiles x CT=4 col-tiles
// (64x64 output); B fragments amortized over the 4 row-tiles (12 MFMAs per
// B pair, 4 independent acc chains). WAVES_N waves split N; remaining waves
// split rows (layer 3). For layers 1/2 each wave's 64 cols = exactly one
// head, so the attention-logit reduce stays within the wave's m-lanes.
// A-frag: m=lane&15, k=quad*8+j. C/D: col=lane&15, row=quad*4+r.
template<int KDIM, int NOUT, int HEADS, int WAVES_N>
__global__ __launch_bounds__(256) void gemm_attn_kernel(
    const __hip_bfloat16* __restrict__ Ah, const __hip_bfloat16* __restrict__ Al,
    const __hip_bfloat16* __restrict__ Bh, const __hip_bfloat16* __restrict__ Bl,
    const float* __restrict__ asv, const float* __restrict__ adv,
    __hip_bfloat16* __restrict__ Ch, float* __restrict__ als, float* __restrict__ ald) {
  constexpr int KCH = KDIM / 32;
  constexpr int CT = (NOUT / 16) / WAVES_N;  // 4
  constexpr int RT = 4;
  constexpr int RGROUPS = 4 / WAVES_N;       // row groups per block
  int wave = threadIdx.x >> 6, lane = threadIdx.x & 63;
  int wrow = wave / WAVES_N, wcol = wave % WAVES_N;
  int rt0 = (blockIdx.x * RGROUPS + wrow) * RT;
  int ct0 = wcol * CT;
  int m = lane & 15, quad = lane >> 4;

  const short8* Bph = reinterpret_cast<const short8*>(Bh);
  const short8* Bpl = reinterpret_cast<const short8*>(Bl);

  floatx4 acc[RT][CT];
#pragma unroll
  for (int rt = 0; rt < RT; ++rt)
#pragma unroll
    for (int ct = 0; ct < CT; ++ct) acc[rt][ct] = (floatx4){0.f, 0.f, 0.f, 0.f};

#pragma unroll 2
  for (int kk = 0; kk < KCH; ++kk) {
    short8 a_h[RT], a_l[RT];
#pragma unroll
    for (int rt = 0; rt < RT; ++rt) {
      size_t aoff = (size_t)((rt0 + rt) * 16 + m) * KDIM + kk * 32 + quad * 8;
      a_h[rt] = *reinterpret_cast<const short8*>(Ah + aoff);
      a_l[rt] = *reinterpret_cast<const short8*>(Al + aoff);
    }
#pragma unroll
    for (int ct = 0; ct < CT; ++ct) {
      size_t o = ((size_t)(ct0 + ct) * KCH + kk) * 64 + lane;
      short8 b_h = Bph[o];
      short8 b_l = Bpl[o];
#pragma unroll
      for (int rt = 0; rt < RT; ++rt) {
        acc[rt][ct] = __builtin_amdgcn_mfma_f32_16x16x32_bf16(a_h[rt], b_h, acc[rt][ct], 0, 0, 0);
        acc[rt][ct] = __builtin_amdgcn_mfma_f32_16x16x32_bf16(a_h[rt], b_l, acc[rt][ct], 0, 0, 0);
        acc[rt][ct] = __builtin_amdgcn_mfma_f32_16x16x32_bf16(a_l[rt], b_h, acc[rt][ct], 0, 0, 0);
      }
    }
  }

  // fused attention logits: this wave's CT*16 cols lie in exactly one head
  constexpr int CPH = NOUT / HEADS;
  int head = (ct0 * 16) / CPH;
  float asl[CT], adl[CT];
#pragma unroll
  for (int ct = 0; ct < CT; ++ct) {
    asl[ct] = asv[(ct0 + ct) * 16 + m];
    adl[ct] = adv[(ct0 + ct) * 16 + m];
  }
  float ps[RT * 4], pd[RT * 4];
#pragma unroll
  for (int i = 0; i < RT * 4; ++i) { ps[i] = 0.f; pd[i] = 0.f; }
#pragma unroll
  for (int rt = 0; rt < RT; ++rt)
#pragma unroll
    for (int ct = 0; ct < CT; ++ct)
#pragma unroll
      for (int r = 0; r < 4; ++r) {
        ps[rt * 4 + r] += acc[rt][ct][r] * asl[ct];
        pd[rt * 4 + r] += acc[rt][ct][r] * adl[ct];
      }
#pragma unroll
  for (int off = 1; off < 16; off <<= 1) {
#pragma unroll
    for (int i = 0; i < RT * 4; ++i) {
      ps[i] += __shfl_xor(ps[i], off);
      pd[i] += __shfl_xor(pd[i], off);
    }
  }
  if (m == 0) {
#pragma unroll
    for (int rt = 0; rt < RT; ++rt)
#pragma unroll
      for (int r = 0; r < 4; ++r) {
        int row = (rt0 + rt) * 16 + quad * 4 + r;
        if (row < NNODES) {
          als[(size_t)row * HEADS + head] = sane(ps[rt * 4 + r], 80.f);
          ald[(size_t)row * HEADS + head] = sane(pd[rt * 4 + r], 80.f);
        }
      }
  }

  // store C (hi-only bf16, row-major for the aggregation gather)
#pragma unroll
  for (int rt = 0; rt < RT; ++rt)
#pragma unroll
    for (int ct = 0; ct < CT; ++ct)
#pragma unroll
      for (int r = 0; r < 4; ++r) {
        int row = (rt0 + rt) * 16 + quad * 4 + r;
        if (row < NNODES) {
          float v = sane(acc[rt][ct][r], 3e4f);
          Ch[(size_t)row * NOUT + (ct0 + ct) * 16 + m] = f2bf(v);
        }
      }
}

// ---------------- normalized edge weights (alpha) ----------------
// one wave per dst node; lane-per-edge; shuffle-reduce denominators
template<int H>
__global__ __launch_bounds__(256) void alpha_kernel(const int* __restrict__ row_ptr,
                                                    const int* __restrict__ csr_src,
                                                    const float* __restrict__ als,
                                                    const float* __restrict__ ald,
                                                    float* __restrict__ alpha) {
  int wid = threadIdx.x >> 6, lane = threadIdx.x & 63;
  int dst = blockIdx.x * 4 + wid;
  if (dst >= NNODES) return;
  int start = row_ptr[dst], end = row_ptr[dst + 1];
  int cnt = end - start;
  if (cnt <= 0) return;
  float adv[H];
#pragma unroll
  for (int h = 0; h < H; ++h) adv[h] = ald[(size_t)dst * H + h];

  if (cnt <= 64) {
    int i = start + lane;
    bool valid = lane < cnt;
    int s = valid ? min(max(csr_src[i], 0), NNODES - 1) : 0;
    float w[H];
#pragma unroll
    for (int h = 0; h < H; ++h) {
      float e = als[(size_t)s * H + h] + adv[h];
      e = e > 0.f ? e : 0.2f * e;
      e = fminf(fmaxf(e, -80.f), 80.f);
      w[h] = valid ? __expf(e) : 0.f;
    }
#pragma unroll
    for (int h = 0; h < H; ++h) {
      float v = w[h];
#pragma unroll
      for (int off = 1; off < 64; off <<= 1) v += __shfl_xor(v, off);
      float inv = 1.f / fmaxf(v, 1e-30f);
      if (valid) alpha[(size_t)i * H + h] = w[h] * inv;
    }
  } else {
    float dl[H];
#pragma unroll
    for (int h = 0; h < H; ++h) dl[h] = 0.f;
    for (int base = start; base < end; base += 64) {
      int i = base + lane;
      bool valid = i < end;
      int s = valid ? min(max(csr_src[i], 0), NNODES - 1) : 0;
#pragma unroll
      for (int h = 0; h < H; ++h) {
        float e = als[(size_t)s * H + h] + adv[h];
        e = e > 0.f ? e : 0.2f * e;
        e = fminf(fmaxf(e, -80.f), 80.f);
        float w = valid ? __expf(e) : 0.f;
        dl[h] += w;
        if (valid) alpha[(size_t)i * H + h] = w;
      }
    }
    float inv[H];
#pragma unroll
    for (int h = 0; h < H; ++h) {
      float v = dl[h];
#pragma unroll
      for (int off = 1; off < 64; off <<= 1) v += __shfl_xor(v, off);
      inv[h] = 1.f / fmaxf(v, 1e-30f);
    }
    for (int base = start; base < end; base += 64) {
      int i = base + lane;
      if (i < end)
#pragma unroll
        for (int h = 0; h < H; ++h) alpha[(size_t)i * H + h] *= inv[h];
    }
  }
}

// ---------------- aggregation, mid layers (T=256, H=4) ----------------
// block = 4 waves per dst; lane owns 4 cols (one dwordx2 bf16x4 load);
// waves stride edges; LDS cross-wave reduce; ELU + hi/lo split epilogue.
__global__ __launch_bounds__(256) void agg_mid_kernel(const int* __restrict__ row_ptr,
                                                      const int* __restrict__ csr_src,
                                                      const __hip_bfloat16* __restrict__ Fh,
                                                      const float* __restrict__ alpha,
                                                      const float* __restrict__ bias,
                                                      __hip_bfloat16* __restrict__ Oh,
                                                      __hip_bfloat16* __restrict__ Ol) {
  __shared__ float part[4][256];
  int dst = blockIdx.x;
  int wid = threadIdx.x >> 6, lane = threadIdx.x & 63;
  int start = row_ptr[dst], end = row_ptr[dst + 1];
  int cnt = end - start;
  int head = lane >> 4;
  float a0 = 0.f, a1 = 0.f, a2 = 0.f, a3 = 0.f;
  int p = wid;
  for (; p + 4 < cnt; p += 8) {  // 2 edges in flight per wave
    int e0 = start + p, e1 = start + p + 4;
    int s0 = csr_src[e0], s1 = csr_src[e1];
    float w0 = alpha[(size_t)e0 * 4 + head];
    float w1 = alpha[(size_t)e1 * 4 + head];
    uint2v f0 = *reinterpret_cast<const uint2v*>(Fh + (size_t)s0 * 256 + lane * 4);
    uint2v f1 = *reinterpret_cast<const uint2v*>(Fh + (size_t)s1 * 256 + lane * 4);
    a0 += w0 * __uint_as_float(f0.x << 16);
    a1 += w0 * __uint_as_float(f0.x & 0xffff0000u);
    a2 += w0 * __uint_as_float(f0.y << 16);
    a3 += w0 * __uint_as_float(f0.y & 0xffff0000u);
    a0 += w1 * __uint_as_float(f1.x << 16);
    a1 += w1 * __uint_as_float(f1.x & 0xffff0000u);
    a2 += w1 * __uint_as_float(f1.y << 16);
    a3 += w1 * __uint_as_float(f1.y & 0xffff0000u);
  }
  for (; p < cnt; p += 4) {
    int e0 = start + p;
    int s0 = csr_src[e0];
    float w0 = alpha[(size_t)e0 * 4 + head];
    uint2v f0 = *reinterpret_cast<const uint2v*>(Fh + (size_t)s0 * 256 + lane * 4);
    a0 += w0 * __uint_as_float(f0.x << 16);
    a1 += w0 * __uint_as_float(f0.x & 0xffff0000u);
    a2 += w0 * __uint_as_float(f0.y << 16);
    a3 += w0 * __uint_as_float(f0.y & 0xffff0000u);
  }
  *reinterpret_cast<floatx4*>(&part[wid][lane * 4]) = (floatx4){a0, a1, a2, a3};
  __syncthreads();
  int t = threadIdx.x;
  float o = part[0][t] + part[1][t] + part[2][t] + part[3][t] + bias[t];
  o = o > 0.f ? o : __expf(o) - 1.f;  // ELU
  __hip_bfloat16 h = f2bf(o);
  Oh[(size_t)dst * 256 + t] = h;
  Ol[(size_t)dst * 256 + t] = f2bf(o - bf2f(h));
}

// ---------------- aggregation, final layer (64-pad feat, 47 out, fp32) ------
__global__ void agg_final_kernel(const int* __restrict__ row_ptr,
                                 const int* __restrict__ csr_src,
                                 const __hip_bfloat16* __restrict__ Fh,
                                 const float* __restrict__ alpha,
                                 const float* __restrict__ bias,
                                 float* __restrict__ out) {
  int wid = threadIdx.x >> 6, lane = threadIdx.x & 63;
  int dst = blockIdx.x * 4 + wid;
  if (dst >= NNODES) return;
  int start = row_ptr[dst], end = row_ptr[dst + 1];
  float acc = 0.f;
  int e = start;
  for (; e + 1 < end; e += 2) {
    int s0 = csr_src[e], s1 = csr_src[e + 1];
    float w0 = alpha[e], w1 = alpha[e + 1];
    float f0 = bf2f(Fh[(size_t)s0 * 64 + lane]);
    float f1 = bf2f(Fh[(size_t)s1 * 64 + lane]);
    acc += w0 * f0 + w1 * f1;
  }
  for (; e < end; ++e) {
    int s0 = csr_src[e];
    acc += alpha[e] * bf2f(Fh[(size_t)s0 * 64 + lane]);
  }
  if (lane < 47) out[(size_t)dst * 47 + lane] = acc + bias[lane];
}

// ---------------- launch ----------------
extern "C" void kernel_launch(void* const* d_in, const int* in_sizes, int n_in,
                              void* d_out, int out_size, void* d_ws, size_t ws_size,
                              hipStream_t stream) {
  const float* x   = (const float*)d_in[0];
  const int* ei    = (const int*)d_in[1];
  const float* W1  = (const float*)d_in[2];
  const float* a1s = (const float*)d_in[3];
  const float* a1d = (const float*)d_in[4];
  const float* b1  = (const float*)d_in[5];
  const float* W2  = (const float*)d_in[6];
  const float* a2s = (const float*)d_in[7];
  const float* a2d = (const float*)d_in[8];
  const float* b2  = (const float*)d_in[9];
  const float* W3  = (const float*)d_in[10];
  const float* a3s = (const float*)d_in[11];
  const float* a3d = (const float*)d_in[12];
  const float* b3  = (const float*)d_in[13];
  float* out = (float*)d_out;
  (void)n_in; (void)in_sizes;

  char* base = (char*)d_ws;
  size_t off = 0;
  auto alloc = [&](size_t bytes) -> char* {
    off = (off + 255) & ~(size_t)255;
    char* p = base + off;
    off += bytes;
    return p;
  };
  int* deg     = (int*)alloc((size_t)NNODES * 4);
  int* cursor  = (int*)alloc((size_t)NNODES * 4);
  int* row_ptr = (int*)alloc((size_t)(NNODES + 1) * 4);
  int* csr_src = (int*)alloc((size_t)ETOT * 4);
  float* als   = (float*)alloc((size_t)NNODES * 4 * 4);
  float* ald   = (float*)alloc((size_t)NNODES * 4 * 4);
  float* alpha = (float*)alloc((size_t)ETOT * 4 * 4);
  __hip_bfloat16* Ah = (__hip_bfloat16*)alloc((size_t)MPAD * 256 * 2);
  __hip_bfloat16* Al = (__hip_bfloat16*)alloc((size_t)MPAD * 256 * 2);
  __hip_bfloat16* Fh = (__hip_bfloat16*)alloc((size_t)NNODES * 256 * 2);
  __hip_bfloat16* wth = (__hip_bfloat16*)alloc((size_t)256 * 256 * 2);
  __hip_bfloat16* wtl = (__hip_bfloat16*)alloc((size_t)256 * 256 * 2);
  float* asv3 = (float*)alloc(64 * 4);
  float* adv3 = (float*)alloc(64 * 4);

  if (ws_size < off) {
    fill_out_kernel<<<(out_size + 255) / 256, 256, 0, stream>>>(out, out_size, 12345.f);
    return;
  }

  // CSR build (shared by all layers)
  zero_int_kernel<<<(NNODES + 255) / 256, 256, 0, stream>>>(deg, NNODES);
  degree_kernel<<<(ETOT + 255) / 256, 256, 0, stream>>>(ei, deg);
  scan_kernel<<<1, 1024, 0, stream>>>(deg, row_ptr, cursor);
  scatter_kernel<<<(ETOT + 255) / 256, 256, 0, stream>>>(ei, cursor, csr_src);

  split_input_kernel<<<(NNODES * 128 + 255) / 256, 256, 0, stream>>>(x, Ah, Al, NNODES * 128);
  {
    const int tail = MPAD * 256 - NNODES * 128;
    zero_tail_kernel<<<(tail + 255) / 256, 256, 0, stream>>>(Ah, Al);
  }
  pad47_kernel<<<1, 64, 0, stream>>>(a3s, a3d, asv3, adv3);

  // layers 1/2: blocks of 64 rows (4 row-tiles), 4 waves split 256 cols
  const int grid12 = (NNODES + 63) / 64;       // 782
  // layer 3: blocks of 256 rows (4 row groups x 4 row-tiles), each wave all 64 cols
  const int grid3 = (NNODES + 255) / 256;      // 196

  // layer 1: 128 -> 4x64, ELU
  pack_w_kernel<<<(256 * 128 + 255) / 256, 256, 0, stream>>>(W1, wth, wtl, 128, 256, 256);
  gemm_attn_kernel<128, 256, 4, 4><<<grid12, 256, 0, stream>>>(Ah, Al, wth, wtl, a1s, a1d,
                                                               Fh, als, ald);
  alpha_kernel<4><<<(NNODES + 3) / 4, 256, 0, stream>>>(row_ptr, csr_src, als, ald, alpha);
  agg_mid_kernel<<<NNODES, 256, 0, stream>>>(row_ptr, csr_src, Fh, alpha, b1, Ah, Al);

  // layer 2: 256 -> 4x64, ELU
  pack_w_kernel<<<(256 * 256 + 255) / 256, 256, 0, stream>>>(W2, wth, wtl, 256, 256, 256);
  gemm_attn_kernel<256, 256, 4, 4><<<grid12, 256, 0, stream>>>(Ah, Al, wth, wtl, a2s, a2d,
                                                               Fh, als, ald);
  alpha_kernel<4><<<(NNODES + 3) / 4, 256, 0, stream>>>(row_ptr, csr_src, als, ald, alpha);
  agg_mid_kernel<<<NNODES, 256, 0, stream>>>(row_ptr, csr_src, Fh, alpha, b2, Ah, Al);

  // layer 3: 256 -> 47 (pad 64), no ELU, fp32 out
  pack_w_kernel<<<(64 * 256 + 255) / 256, 256, 0, stream>>>(W3, wth, wtl, 256, 47, 64);
  gemm_attn_kernel<256, 64, 1, 1><<<grid3, 256, 0, stream>>>(Ah, Al, wth, wtl, asv3, adv3,
                                                             Fh, als, ald);
  alpha_kernel<1><<<(NNODES + 3) / 4, 256, 0, stream>>>(row_ptr, csr_src, als, ald, alpha);
  agg_final_kernel<<<(NNODES + 3) / 4, 256, 0, stream>>>(row_ptr, csr_src, Fh, alpha, b3, out);
}

// Round 5
// 574.793 us; speedup vs baseline: 1.4293x; 1.2647x over previous
//
#include <hip/hip_runtime.h>
#include <hip/hip_bf16.h>

#define NNODES 50000
#define NEDGES 800000
#define ETOT   (NNODES + NEDGES)
#define MTILES 3136            // row-tiles of 16: covers 50176 rows
#define MPAD   (MTILES * 16)   // 50176
#define NBLK   196             // ceil(NNODES/256) for the scan

typedef __attribute__((ext_vector_type(8))) short short8;
typedef __attribute__((ext_vector_type(4))) float floatx4;
typedef __attribute__((ext_vector_type(2))) unsigned int uint2v;

__device__ __forceinline__ float bf2f(__hip_bfloat16 x) { return __bfloat162float(x); }
__device__ __forceinline__ __hip_bfloat16 f2bf(float f) { return __float2bfloat16(f); }
__device__ __forceinline__ float sane(float v, float c) {
  v = (v == v) ? v : 0.f;
  return fminf(fmaxf(v, -c), c);
}

// ---------------- utility ----------------
__global__ void zero_int_kernel(int* __restrict__ p, int n) {
  int i = blockIdx.x * blockDim.x + threadIdx.x;
  if (i < n) p[i] = 0;
}
__global__ void fill_out_kernel(float* __restrict__ o, int n, float v) {
  int i = blockIdx.x * blockDim.x + threadIdx.x;
  if (i < n) o[i] = v;
}
__global__ void split_input_kernel(const float* __restrict__ in,
                                   __hip_bfloat16* __restrict__ hi,
                                   __hip_bfloat16* __restrict__ lo, int n) {
  int i = blockIdx.x * blockDim.x + threadIdx.x;
  if (i >= n) return;
  float v = sane(in[i], 1e4f);
  __hip_bfloat16 h = f2bf(v);
  hi[i] = h;
  lo[i] = f2bf(v - bf2f(h));
}
// zero the A-buffer tail so pad-row reads (any stride 128/256) see zeros
__global__ void zero_tail_kernel(__hip_bfloat16* __restrict__ hi,
                                 __hip_bfloat16* __restrict__ lo) {
  const int base = NNODES * 128;
  const int cnt = MPAD * 256 - base;
  int i = blockIdx.x * blockDim.x + threadIdx.x;
  if (i >= cnt) return;
  hi[base + i] = f2bf(0.f);
  lo[base + i] = f2bf(0.f);
}
// pad 47-vec attention params to 64 with zeros
__global__ void pad47_kernel(const float* __restrict__ a, const float* __restrict__ b,
                             float* __restrict__ ap, float* __restrict__ bp) {
  int i = threadIdx.x;  // 64
  ap[i] = (i < 47) ? sane(a[i], 1e4f) : 0.f;
  bp[i] = (i < 47) ? sane(b[i], 1e4f) : 0.f;
}

// ---------------- CSR build (dst-sorted) ----------------
__global__ void degree_kernel(const int* __restrict__ ei, int* __restrict__ deg) {
  int p = blockIdx.x * blockDim.x + threadIdx.x;
  if (p >= ETOT) return;
  int dst = (p < NEDGES) ? ei[NEDGES + p] : (p - NEDGES);
  dst = min(max(dst, 0), NNODES - 1);
  atomicAdd(&deg[dst], 1);
}

// --- parallel 3-phase scan (replaces the 109us single-block scan) ---
__global__ __launch_bounds__(256) void block_sum_kernel(const int* __restrict__ deg,
                                                        int* __restrict__ bsum) {
  __shared__ int sh[256];
  int b = blockIdx.x, t = threadIdx.x;
  int i = b * 256 + t;
  sh[t] = (i < NNODES) ? deg[i] : 0;
  __syncthreads();
  for (int off = 128; off > 0; off >>= 1) {
    if (t < off) sh[t] += sh[t + off];
    __syncthreads();
  }
  if (t == 0) bsum[b] = sh[0];
}

__global__ __launch_bounds__(256) void scan_bsum_kernel(const int* __restrict__ bsum,
                                                        int* __restrict__ boff,
                                                        int* __restrict__ row_ptr) {
  __shared__ int sh[256];
  int t = threadIdx.x;
  int v = (t < NBLK) ? bsum[t] : 0;
  sh[t] = v;
  __syncthreads();
  for (int off = 1; off < 256; off <<= 1) {
    int u = (t >= off) ? sh[t - off] : 0;
    __syncthreads();
    sh[t] += u;
    __syncthreads();
  }
  if (t < NBLK) boff[t] = sh[t] - v;  // exclusive block offset
  if (t == 255) row_ptr[NNODES] = sh[255];
}

__global__ __launch_bounds__(256) void emit_rowptr_kernel(const int* __restrict__ deg,
                                                          const int* __restrict__ boff,
                                                          int* __restrict__ row_ptr,
                                                          int* __restrict__ cursor) {
  __shared__ int sh[256];
  int b = blockIdx.x, t = threadIdx.x;
  int i = b * 256 + t;
  int d = (i < NNODES) ? deg[i] : 0;
  sh[t] = d;
  __syncthreads();
  for (int off = 1; off < 256; off <<= 1) {
    int u = (t >= off) ? sh[t - off] : 0;
    __syncthreads();
    sh[t] += u;
    __syncthreads();
  }
  if (i < NNODES) {
    int v = boff[b] + sh[t] - d;  // exclusive prefix
    row_ptr[i] = v;
    cursor[i] = v;
  }
}

__global__ void scatter_kernel(const int* __restrict__ ei, int* __restrict__ cursor,
                               int* __restrict__ csr_src) {
  int p = blockIdx.x * blockDim.x + threadIdx.x;
  if (p >= ETOT) return;
  int src, dst;
  if (p < NEDGES) { src = ei[p]; dst = ei[NEDGES + p]; }
  else            { src = p - NEDGES; dst = src; }
  src = min(max(src, 0), NNODES - 1);
  dst = min(max(dst, 0), NNODES - 1);
  int pos = atomicAdd(&cursor[dst], 1);
  pos = min(max(pos, 0), ETOT - 1);
  csr_src[pos] = src;
}

// ---------------- weight pack (W [K][Nreal] f32 -> fragment-packed W^T) -------
// Packed layout: elem(n, k) -> idx = ((nt*KCH + kk32)*64 + quad*16 + m)*8 + j
__global__ void pack_w_kernel(const float* __restrict__ W,
                              __hip_bfloat16* __restrict__ Bh,
                              __hip_bfloat16* __restrict__ Bl,
                              int K, int Nreal, int Npad) {
  int idx = blockIdx.x * blockDim.x + threadIdx.x;
  if (idx >= Npad * K) return;
  int e = idx;
  int j = e & 7;    e >>= 3;
  int m = e & 15;   e >>= 4;
  int quad = e & 3; e >>= 2;
  int kch = K >> 5;
  int kk32 = e % kch;
  int nt = e / kch;
  int n = nt * 16 + m;
  int k = kk32 * 32 + quad * 8 + j;
  float v = (n < Nreal) ? sane(W[k * Nreal + n], 1e4f) : 0.f;
  __hip_bfloat16 h = f2bf(v);
  Bh[idx] = h;
  Bl[idx] = f2bf(v - bf2f(h));
}

// ---------------- GEMM + fused attention logits ----------------
// A row-major in HBM (verified), B fragment-packed (verified), RT=4 x CT
// register blocking (verified bit-exact in R4).
// WAVES_N==4 (layers 1/2): all 4 waves share the block's 64 A-rows, so the
// current kk-step's 64x32 hi/lo A-slice is staged once into LDS:
//   write: thread t -> linear 16B at t*16 (conflict-free floor)
//   read:  fragment (rt,m,quad) at (rt*16+m)*64B + quad*16B
//          chunk class = 4*(m&1)+quad -> 8 classes x 8 lanes = floor
// Values and MFMA order are bitwise identical to the direct-load path.
// WAVES_N==1 (layer 3): waves own different rows; keep direct loads.
template<int KDIM, int NOUT, int HEADS, int WAVES_N>
__global__ __launch_bounds__(256) void gemm_attn_kernel(
    const __hip_bfloat16* __restrict__ Ah, const __hip_bfloat16* __restrict__ Al,
    const __hip_bfloat16* __restrict__ Bh, const __hip_bfloat16* __restrict__ Bl,
    const float* __restrict__ asv, const float* __restrict__ adv,
    __hip_bfloat16* __restrict__ Ch, float* __restrict__ als, float* __restrict__ ald) {
  constexpr int KCH = KDIM / 32;
  constexpr int CT = (NOUT / 16) / WAVES_N;  // 4
  constexpr int RT = 4;
  constexpr int RGROUPS = 4 / WAVES_N;       // row groups per block
  __shared__ __hip_bfloat16 sAh[64 * 32];
  __shared__ __hip_bfloat16 sAl[64 * 32];
  int wave = threadIdx.x >> 6, lane = threadIdx.x & 63;
  int wrow = wave / WAVES_N, wcol = wave % WAVES_N;
  int rt0 = (blockIdx.x * RGROUPS + wrow) * RT;
  int ct0 = wcol * CT;
  int m = lane & 15, quad = lane >> 4;

  const short8* Bph = reinterpret_cast<const short8*>(Bh);
  const short8* Bpl = reinterpret_cast<const short8*>(Bl);

  floatx4 acc[RT][CT];
#pragma unroll
  for (int rt = 0; rt < RT; ++rt)
#pragma unroll
    for (int ct = 0; ct < CT; ++ct) acc[rt][ct] = (floatx4){0.f, 0.f, 0.f, 0.f};

  // staging indices (WAVES_N==4 path)
  int tid = threadIdx.x;
  size_t gstage = (size_t)(rt0 * 16 + (tid >> 2)) * KDIM + (tid & 3) * 8;

#pragma unroll 2
  for (int kk = 0; kk < KCH; ++kk) {
    short8 a_h[RT], a_l[RT];
    if constexpr (WAVES_N == 4) {
      short8 vh = *reinterpret_cast<const short8*>(Ah + gstage + kk * 32);
      short8 vl = *reinterpret_cast<const short8*>(Al + gstage + kk * 32);
      __syncthreads();  // prior kk's reads complete before overwrite
      *reinterpret_cast<short8*>(&sAh[tid * 8]) = vh;
      *reinterpret_cast<short8*>(&sAl[tid * 8]) = vl;
      __syncthreads();
#pragma unroll
      for (int rt = 0; rt < RT; ++rt) {
        int so = (rt * 16 + m) * 32 + quad * 8;
        a_h[rt] = *reinterpret_cast<const short8*>(&sAh[so]);
        a_l[rt] = *reinterpret_cast<const short8*>(&sAl[so]);
      }
    } else {
#pragma unroll
      for (int rt = 0; rt < RT; ++rt) {
        size_t aoff = (size_t)((rt0 + rt) * 16 + m) * KDIM + kk * 32 + quad * 8;
        a_h[rt] = *reinterpret_cast<const short8*>(Ah + aoff);
        a_l[rt] = *reinterpret_cast<const short8*>(Al + aoff);
      }
    }
#pragma unroll
    for (int ct = 0; ct < CT; ++ct) {
      size_t o = ((size_t)(ct0 + ct) * KCH + kk) * 64 + lane;
      short8 b_h = Bph[o];
      short8 b_l = Bpl[o];
#pragma unroll
      for (int rt = 0; rt < RT; ++rt) {
        acc[rt][ct] = __builtin_amdgcn_mfma_f32_16x16x32_bf16(a_h[rt], b_h, acc[rt][ct], 0, 0, 0);
        acc[rt][ct] = __builtin_amdgcn_mfma_f32_16x16x32_bf16(a_h[rt], b_l, acc[rt][ct], 0, 0, 0);
        acc[rt][ct] = __builtin_amdgcn_mfma_f32_16x16x32_bf16(a_l[rt], b_h, acc[rt][ct], 0, 0, 0);
      }
    }
  }

  // fused attention logits: this wave's CT*16 cols lie in exactly one head
  constexpr int CPH = NOUT / HEADS;
  int head = (ct0 * 16) / CPH;
  float asl[CT], adl[CT];
#pragma unroll
  for (int ct = 0; ct < CT; ++ct) {
    asl[ct] = asv[(ct0 + ct) * 16 + m];
    adl[ct] = adv[(ct0 + ct) * 16 + m];
  }
  float ps[RT * 4], pd[RT * 4];
#pragma unroll
  for (int i = 0; i < RT * 4; ++i) { ps[i] = 0.f; pd[i] = 0.f; }
#pragma unroll
  for (int rt = 0; rt < RT; ++rt)
#pragma unroll
    for (int ct = 0; ct < CT; ++ct)
#pragma unroll
      for (int r = 0; r < 4; ++r) {
        ps[rt * 4 + r] += acc[rt][ct][r] * asl[ct];
        pd[rt * 4 + r] += acc[rt][ct][r] * adl[ct];
      }
#pragma unroll
  for (int off = 1; off < 16; off <<= 1) {
#pragma unroll
    for (int i = 0; i < RT * 4; ++i) {
      ps[i] += __shfl_xor(ps[i], off);
      pd[i] += __shfl_xor(pd[i], off);
    }
  }
  if (m == 0) {
#pragma unroll
    for (int rt = 0; rt < RT; ++rt)
#pragma unroll
      for (int r = 0; r < 4; ++r) {
        int row = (rt0 + rt) * 16 + quad * 4 + r;
        if (row < NNODES) {
          als[(size_t)row * HEADS + head] = sane(ps[rt * 4 + r], 80.f);
          ald[(size_t)row * HEADS + head] = sane(pd[rt * 4 + r], 80.f);
        }
      }
  }

  // store C (hi-only bf16, row-major for the aggregation gather)
#pragma unroll
  for (int rt = 0; rt < RT; ++rt)
#pragma unroll
    for (int ct = 0; ct < CT; ++ct)
#pragma unroll
      for (int r = 0; r < 4; ++r) {
        int row = (rt0 + rt) * 16 + quad * 4 + r;
        if (row < NNODES) {
          float v = sane(acc[rt][ct][r], 3e4f);
          Ch[(size_t)row * NOUT + (ct0 + ct) * 16 + m] = f2bf(v);
        }
      }
}

// ---------------- normalized edge weights (alpha) ----------------
template<int H>
__global__ __launch_bounds__(256) void alpha_kernel(const int* __restrict__ row_ptr,
                                                    const int* __restrict__ csr_src,
                                                    const float* __restrict__ als,
                                                    const float* __restrict__ ald,
                                                    float* __restrict__ alpha) {
  int wid = threadIdx.x >> 6, lane = threadIdx.x & 63;
  int dst = blockIdx.x * 4 + wid;
  if (dst >= NNODES) return;
  int start = row_ptr[dst], end = row_ptr[dst + 1];
  int cnt = end - start;
  if (cnt <= 0) return;
  float adv[H];
#pragma unroll
  for (int h = 0; h < H; ++h) adv[h] = ald[(size_t)dst * H + h];

  if (cnt <= 64) {
    int i = start + lane;
    bool valid = lane < cnt;
    int s = valid ? min(max(csr_src[i], 0), NNODES - 1) : 0;
    float w[H];
#pragma unroll
    for (int h = 0; h < H; ++h) {
      float e = als[(size_t)s * H + h] + adv[h];
      e = e > 0.f ? e : 0.2f * e;
      e = fminf(fmaxf(e, -80.f), 80.f);
      w[h] = valid ? __expf(e) : 0.f;
    }
#pragma unroll
    for (int h = 0; h < H; ++h) {
      float v = w[h];
#pragma unroll
      for (int off = 1; off < 64; off <<= 1) v += __shfl_xor(v, off);
      float inv = 1.f / fmaxf(v, 1e-30f);
      if (valid) alpha[(size_t)i * H + h] = w[h] * inv;
    }
  } else {
    float dl[H];
#pragma unroll
    for (int h = 0; h < H; ++h) dl[h] = 0.f;
    for (int base = start; base < end; base += 64) {
      int i = base + lane;
      bool valid = i < end;
      int s = valid ? min(max(csr_src[i], 0), NNODES - 1) : 0;
#pragma unroll
      for (int h = 0; h < H; ++h) {
        float e = als[(size_t)s * H + h] + adv[h];
        e = e > 0.f ? e : 0.2f * e;
        e = fminf(fmaxf(e, -80.f), 80.f);
        float w = valid ? __expf(e) : 0.f;
        dl[h] += w;
        if (valid) alpha[(size_t)i * H + h] = w;
      }
    }
    float inv[H];
#pragma unroll
    for (int h = 0; h < H; ++h) {
      float v = dl[h];
#pragma unroll
      for (int off = 1; off < 64; off <<= 1) v += __shfl_xor(v, off);
      inv[h] = 1.f / fmaxf(v, 1e-30f);
    }
    for (int base = start; base < end; base += 64) {
      int i = base + lane;
      if (i < end)
#pragma unroll
        for (int h = 0; h < H; ++h) alpha[(size_t)i * H + h] *= inv[h];
    }
  }
}

// ---------------- aggregation, mid layers (T=256, H=4) ----------------
__global__ __launch_bounds__(256) void agg_mid_kernel(const int* __restrict__ row_ptr,
                                                      const int* __restrict__ csr_src,
                                                      const __hip_bfloat16* __restrict__ Fh,
                                                      const float* __restrict__ alpha,
                                                      const float* __restrict__ bias,
                                                      __hip_bfloat16* __restrict__ Oh,
                                                      __hip_bfloat16* __restrict__ Ol) {
  __shared__ float part[4][256];
  int dst = blockIdx.x;
  int wid = threadIdx.x >> 6, lane = threadIdx.x & 63;
  int start = row_ptr[dst], end = row_ptr[dst + 1];
  int cnt = end - start;
  int head = lane >> 4;
  float a0 = 0.f, a1 = 0.f, a2 = 0.f, a3 = 0.f;
  int p = wid;
  for (; p + 4 < cnt; p += 8) {  // 2 edges in flight per wave
    int e0 = start + p, e1 = start + p + 4;
    int s0 = csr_src[e0], s1 = csr_src[e1];
    float w0 = alpha[(size_t)e0 * 4 + head];
    float w1 = alpha[(size_t)e1 * 4 + head];
    uint2v f0 = *reinterpret_cast<const uint2v*>(Fh + (size_t)s0 * 256 + lane * 4);
    uint2v f1 = *reinterpret_cast<const uint2v*>(Fh + (size_t)s1 * 256 + lane * 4);
    a0 += w0 * __uint_as_float(f0.x << 16);
    a1 += w0 * __uint_as_float(f0.x & 0xffff0000u);
    a2 += w0 * __uint_as_float(f0.y << 16);
    a3 += w0 * __uint_as_float(f0.y & 0xffff0000u);
    a0 += w1 * __uint_as_float(f1.x << 16);
    a1 += w1 * __uint_as_float(f1.x & 0xffff0000u);
    a2 += w1 * __uint_as_float(f1.y << 16);
    a3 += w1 * __uint_as_float(f1.y & 0xffff0000u);
  }
  for (; p < cnt; p += 4) {
    int e0 = start + p;
    int s0 = csr_src[e0];
    float w0 = alpha[(size_t)e0 * 4 + head];
    uint2v f0 = *reinterpret_cast<const uint2v*>(Fh + (size_t)s0 * 256 + lane * 4);
    a0 += w0 * __uint_as_float(f0.x << 16);
    a1 += w0 * __uint_as_float(f0.x & 0xffff0000u);
    a2 += w0 * __uint_as_float(f0.y << 16);
    a3 += w0 * __uint_as_float(f0.y & 0xffff0000u);
  }
  *reinterpret_cast<floatx4*>(&part[wid][lane * 4]) = (floatx4){a0, a1, a2, a3};
  __syncthreads();
  int t = threadIdx.x;
  float o = part[0][t] + part[1][t] + part[2][t] + part[3][t] + bias[t];
  o = o > 0.f ? o : __expf(o) - 1.f;  // ELU
  __hip_bfloat16 h = f2bf(o);
  Oh[(size_t)dst * 256 + t] = h;
  Ol[(size_t)dst * 256 + t] = f2bf(o - bf2f(h));
}

// ---------------- aggregation, final layer (64-pad feat, 47 out, fp32) ------
__global__ void agg_final_kernel(const int* __restrict__ row_ptr,
                                 const int* __restrict__ csr_src,
                                 const __hip_bfloat16* __restrict__ Fh,
                                 const float* __restrict__ alpha,
                                 const float* __restrict__ bias,
                                 float* __restrict__ out) {
  int wid = threadIdx.x >> 6, lane = threadIdx.x & 63;
  int dst = blockIdx.x * 4 + wid;
  if (dst >= NNODES) return;
  int start = row_ptr[dst], end = row_ptr[dst + 1];
  float acc = 0.f;
  int e = start;
  for (; e + 1 < end; e += 2) {
    int s0 = csr_src[e], s1 = csr_src[e + 1];
    float w0 = alpha[e], w1 = alpha[e + 1];
    float f0 = bf2f(Fh[(size_t)s0 * 64 + lane]);
    float f1 = bf2f(Fh[(size_t)s1 * 64 + lane]);
    acc += w0 * f0 + w1 * f1;
  }
  for (; e < end; ++e) {
    int s0 = csr_src[e];
    acc += alpha[e] * bf2f(Fh[(size_t)s0 * 64 + lane]);
  }
  if (lane < 47) out[(size_t)dst * 47 + lane] = acc + bias[lane];
}

// ---------------- launch ----------------
extern "C" void kernel_launch(void* const* d_in, const int* in_sizes, int n_in,
                              void* d_out, int out_size, void* d_ws, size_t ws_size,
                              hipStream_t stream) {
  const float* x   = (const float*)d_in[0];
  const int* ei    = (const int*)d_in[1];
  const float* W1  = (const float*)d_in[2];
  const float* a1s = (const float*)d_in[3];
  const float* a1d = (const float*)d_in[4];
  const float* b1  = (const float*)d_in[5];
  const float* W2  = (const float*)d_in[6];
  const float* a2s = (const float*)d_in[7];
  const float* a2d = (const float*)d_in[8];
  const float* b2  = (const float*)d_in[9];
  const float* W3  = (const float*)d_in[10];
  const float* a3s = (const float*)d_in[11];
  const float* a3d = (const float*)d_in[12];
  const float* b3  = (const float*)d_in[13];
  float* out = (float*)d_out;
  (void)n_in; (void)in_sizes;

  char* base = (char*)d_ws;
  size_t off = 0;
  auto alloc = [&](size_t bytes) -> char* {
    off = (off + 255) & ~(size_t)255;
    char* p = base + off;
    off += bytes;
    return p;
  };
  int* deg     = (int*)alloc((size_t)NNODES * 4);
  int* cursor  = (int*)alloc((size_t)NNODES * 4);
  int* row_ptr = (int*)alloc((size_t)(NNODES + 1) * 4);
  int* csr_src = (int*)alloc((size_t)ETOT * 4);
  int* bsum    = (int*)alloc(256 * 4);
  int* boff    = (int*)alloc(256 * 4);
  float* als   = (float*)alloc((size_t)NNODES * 4 * 4);
  float* ald   = (float*)alloc((size_t)NNODES * 4 * 4);
  float* alpha = (float*)alloc((size_t)ETOT * 4 * 4);
  __hip_bfloat16* Ah = (__hip_bfloat16*)alloc((size_t)MPAD * 256 * 2);
  __hip_bfloat16* Al = (__hip_bfloat16*)alloc((size_t)MPAD * 256 * 2);
  __hip_bfloat16* Fh = (__hip_bfloat16*)alloc((size_t)NNODES * 256 * 2);
  __hip_bfloat16* wth = (__hip_bfloat16*)alloc((size_t)256 * 256 * 2);
  __hip_bfloat16* wtl = (__hip_bfloat16*)alloc((size_t)256 * 256 * 2);
  float* asv3 = (float*)alloc(64 * 4);
  float* adv3 = (float*)alloc(64 * 4);

  if (ws_size < off) {
    fill_out_kernel<<<(out_size + 255) / 256, 256, 0, stream>>>(out, out_size, 12345.f);
    return;
  }

  // CSR build (shared by all layers) — parallel 3-phase scan
  zero_int_kernel<<<(NNODES + 255) / 256, 256, 0, stream>>>(deg, NNODES);
  degree_kernel<<<(ETOT + 255) / 256, 256, 0, stream>>>(ei, deg);
  block_sum_kernel<<<NBLK, 256, 0, stream>>>(deg, bsum);
  scan_bsum_kernel<<<1, 256, 0, stream>>>(bsum, boff, row_ptr);
  emit_rowptr_kernel<<<NBLK, 256, 0, stream>>>(deg, boff, row_ptr, cursor);
  scatter_kernel<<<(ETOT + 255) / 256, 256, 0, stream>>>(ei, cursor, csr_src);

  split_input_kernel<<<(NNODES * 128 + 255) / 256, 256, 0, stream>>>(x, Ah, Al, NNODES * 128);
  {
    const int tail = MPAD * 256 - NNODES * 128;
    zero_tail_kernel<<<(tail + 255) / 256, 256, 0, stream>>>(Ah, Al);
  }
  pad47_kernel<<<1, 64, 0, stream>>>(a3s, a3d, asv3, adv3);

  // layers 1/2: blocks of 64 rows (4 row-tiles), 4 waves split 256 cols
  const int grid12 = (NNODES + 63) / 64;       // 782
  // layer 3: blocks of 256 rows (4 row groups x 4 row-tiles), each wave all 64 cols
  const int grid3 = (NNODES + 255) / 256;      // 196

  // layer 1: 128 -> 4x64, ELU
  pack_w_kernel<<<(256 * 128 + 255) / 256, 256, 0, stream>>>(W1, wth, wtl, 128, 256, 256);
  gemm_attn_kernel<128, 256, 4, 4><<<grid12, 256, 0, stream>>>(Ah, Al, wth, wtl, a1s, a1d,
                                                               Fh, als, ald);
  alpha_kernel<4><<<(NNODES + 3) / 4, 256, 0, stream>>>(row_ptr, csr_src, als, ald, alpha);
  agg_mid_kernel<<<NNODES, 256, 0, stream>>>(row_ptr, csr_src, Fh, alpha, b1, Ah, Al);

  // layer 2: 256 -> 4x64, ELU
  pack_w_kernel<<<(256 * 256 + 255) / 256, 256, 0, stream>>>(W2, wth, wtl, 256, 256, 256);
  gemm_attn_kernel<256, 256, 4, 4><<<grid12, 256, 0, stream>>>(Ah, Al, wth, wtl, a2s, a2d,
                                                               Fh, als, ald);
  alpha_kernel<4><<<(NNODES + 3) / 4, 256, 0, stream>>>(row_ptr, csr_src, als, ald, alpha);
  agg_mid_kernel<<<NNODES, 256, 0, stream>>>(row_ptr, csr_src, Fh, alpha, b2, Ah, Al);

  // layer 3: 256 -> 47 (pad 64), no ELU, fp32 out
  pack_w_kernel<<<(64 * 256 + 255) / 256, 256, 0, stream>>>(W3, wth, wtl, 256, 47, 64);
  gemm_attn_kernel<256, 64, 1, 1><<<grid3, 256, 0, stream>>>(Ah, Al, wth, wtl, asv3, adv3,
                                                             Fh, als, ald);
  alpha_kernel<1><<<(NNODES + 3) / 4, 256, 0, stream>>>(row_ptr, csr_src, als, ald, alpha);
  agg_final_kernel<<<(NNODES + 3) / 4, 256, 0, stream>>>(row_ptr, csr_src, Fh, alpha, b3, out);
}